// Round 1
// baseline (572.840 us; speedup 1.0000x reference)
//
#include <hip/hip_runtime.h>

#define N_NODES 50000
#define N_EDGES 600000
#define DIN 128
#define HD 128
#define DOUT 64

// ---------------- degree histogram ----------------
__global__ __launch_bounds__(256) void deg_kernel(const int* __restrict__ ei,
                                                  float* __restrict__ deg) {
    int e = blockIdx.x * 256 + threadIdx.x;
    if (e < N_EDGES) {
        int t = ei[N_EDGES + e];  // dst row
        atomicAdd(&deg[t], 1.0f);
    }
}

// ---------------- layer-1 scatter: agg[dst] += x[src], 128-wide ----------------
__global__ __launch_bounds__(256) void scatter1_kernel(const int* __restrict__ ei,
                                                       const float* __restrict__ x,
                                                       float* __restrict__ agg) {
    int gid = blockIdx.x * 256 + threadIdx.x;  // < E*128
    int e = gid >> 7;
    int d = gid & 127;
    int s = ei[e];
    int t = ei[N_EDGES + e];
    atomicAdd(&agg[t * DIN + d], x[s * DIN + d]);
}

// ---------------- layer 1: h = relu(agg@w1l/deg + b1 + x@w1r) ----------------
// block = 256 thr (4 waves), 16 nodes/block, wave handles 4 nodes x 2 cols/lane
__global__ __launch_bounds__(256) void layer1_kernel(
    const float* __restrict__ x, const float* __restrict__ agg,
    const float* __restrict__ deg,
    const float* __restrict__ w1l, const float* __restrict__ b1,
    const float* __restrict__ w1r, float* __restrict__ h) {
    __shared__ float sA[16 * DIN];
    __shared__ float sX[16 * DIN];
    const int block0 = blockIdx.x * 16;

    const float4* av = (const float4*)(agg + (size_t)block0 * DIN);
    const float4* xv = (const float4*)(x + (size_t)block0 * DIN);
    float4* sav = (float4*)sA;
    float4* sxv = (float4*)sX;
    for (int i = threadIdx.x; i < 16 * DIN / 4; i += 256) {
        sav[i] = av[i];
        sxv[i] = xv[i];
    }
    __syncthreads();

    const int wave = threadIdx.x >> 6, lane = threadIdx.x & 63;
    const int r0 = wave * 4;
    float aA0[4], aA1[4], aX0[4], aX1[4];
#pragma unroll
    for (int m = 0; m < 4; m++) { aA0[m] = aA1[m] = aX0[m] = aX1[m] = 0.f; }

    for (int k = 0; k < DIN; k++) {
        float wl0 = w1l[k * HD + lane];
        float wl1 = w1l[k * HD + 64 + lane];
        float wr0 = w1r[k * HD + lane];
        float wr1 = w1r[k * HD + 64 + lane];
#pragma unroll
        for (int m = 0; m < 4; m++) {
            float a = sA[(r0 + m) * DIN + k];  // wave-uniform -> LDS broadcast
            float b = sX[(r0 + m) * DIN + k];
            aA0[m] = fmaf(a, wl0, aA0[m]);
            aA1[m] = fmaf(a, wl1, aA1[m]);
            aX0[m] = fmaf(b, wr0, aX0[m]);
            aX1[m] = fmaf(b, wr1, aX1[m]);
        }
    }

    float bb0 = b1[lane], bb1 = b1[64 + lane];
#pragma unroll
    for (int m = 0; m < 4; m++) {
        int node = block0 + r0 + m;
        float invd = 1.0f / fmaxf(deg[node], 1.0f);
        float v0 = fmaf(aA0[m], invd, aX0[m]) + bb0;
        float v1 = fmaf(aA1[m], invd, aX1[m]) + bb1;
        h[(size_t)node * HD + lane] = fmaxf(v0, 0.f);
        h[(size_t)node * HD + 64 + lane] = fmaxf(v1, 0.f);
    }
}

// ---------------- layer-2 pre-transform: p = h@w2l ; out = h@w2r + b2 ----------------
__global__ __launch_bounds__(256) void transform2_kernel(
    const float* __restrict__ h,
    const float* __restrict__ w2l, const float* __restrict__ b2,
    const float* __restrict__ w2r,
    float* __restrict__ p, float* __restrict__ outq) {
    __shared__ float sH[16 * HD];
    const int block0 = blockIdx.x * 16;
    const float4* hv = (const float4*)(h + (size_t)block0 * HD);
    float4* shv = (float4*)sH;
    for (int i = threadIdx.x; i < 16 * HD / 4; i += 256) shv[i] = hv[i];
    __syncthreads();

    const int wave = threadIdx.x >> 6, lane = threadIdx.x & 63;
    const int r0 = wave * 4;
    float aP[4] = {0, 0, 0, 0}, aQ[4] = {0, 0, 0, 0};
    for (int k = 0; k < HD; k++) {
        float wl = w2l[k * DOUT + lane];
        float wr = w2r[k * DOUT + lane];
#pragma unroll
        for (int m = 0; m < 4; m++) {
            float v = sH[(r0 + m) * HD + k];
            aP[m] = fmaf(v, wl, aP[m]);
            aQ[m] = fmaf(v, wr, aQ[m]);
        }
    }
    float bb = b2[lane];
#pragma unroll
    for (int m = 0; m < 4; m++) {
        int node = block0 + r0 + m;
        p[(size_t)node * DOUT + lane] = aP[m];
        outq[(size_t)node * DOUT + lane] = aQ[m] + bb;
    }
}

// ---------------- layer-2 scatter: agg2[dst] += p[src], 64-wide ----------------
__global__ __launch_bounds__(256) void scatter2_kernel(const int* __restrict__ ei,
                                                       const float* __restrict__ p,
                                                       float* __restrict__ agg2) {
    int gid = blockIdx.x * 256 + threadIdx.x;  // < E*64
    int e = gid >> 6;
    int d = gid & 63;
    int s = ei[e];
    int t = ei[N_EDGES + e];
    atomicAdd(&agg2[t * DOUT + d], p[s * DOUT + d]);
}

// ---------------- finish: out += agg2/deg ----------------
__global__ __launch_bounds__(256) void final_kernel(const float* __restrict__ agg2,
                                                    const float* __restrict__ deg,
                                                    float* __restrict__ out) {
    int gid = blockIdx.x * 256 + threadIdx.x;  // < N*64
    int n = gid >> 6;
    float invd = 1.0f / fmaxf(deg[n], 1.0f);
    out[gid] = fmaf(agg2[gid], invd, out[gid]);
}

extern "C" void kernel_launch(void* const* d_in, const int* in_sizes, int n_in,
                              void* d_out, int out_size, void* d_ws, size_t ws_size,
                              hipStream_t stream) {
    const float* x   = (const float*)d_in[0];
    const int*   ei  = (const int*)d_in[1];   // [2, E] (src row, then dst row)
    const float* w1l = (const float*)d_in[2];
    const float* b1  = (const float*)d_in[3];
    const float* w1r = (const float*)d_in[4];
    const float* w2l = (const float*)d_in[5];
    const float* b2  = (const float*)d_in[6];
    const float* w2r = (const float*)d_in[7];
    float* out = (float*)d_out;

    float* ws  = (float*)d_ws;
    float* agg = ws;                                   // N*128 (also reused as agg2: N*64)
    float* deg = agg + (size_t)N_NODES * DIN;          // N
    float* h   = deg + N_NODES;                        // N*128
    float* p   = h + (size_t)N_NODES * HD;             // N*64
    // total ws use: (N*128 + N + N*128 + N*64) * 4B = 64.2 MB

    // zero agg + deg (contiguous)
    hipMemsetAsync(agg, 0, ((size_t)N_NODES * DIN + N_NODES) * sizeof(float), stream);

    deg_kernel<<<(N_EDGES + 255) / 256, 256, 0, stream>>>(ei, deg);
    scatter1_kernel<<<(N_EDGES * DIN) / 256, 256, 0, stream>>>(ei, x, agg);
    layer1_kernel<<<N_NODES / 16, 256, 0, stream>>>(x, agg, deg, w1l, b1, w1r, h);
    transform2_kernel<<<N_NODES / 16, 256, 0, stream>>>(h, w2l, b2, w2r, p, out);

    // re-zero agg region for layer-2 aggregation (N*64 floats)
    hipMemsetAsync(agg, 0, (size_t)N_NODES * DOUT * sizeof(float), stream);
    scatter2_kernel<<<(N_EDGES * DOUT) / 256, 256, 0, stream>>>(ei, p, agg);
    final_kernel<<<(N_NODES * DOUT) / 256, 256, 0, stream>>>(agg, deg, out);
}

// Round 2
// 339.741 us; speedup vs baseline: 1.6861x; 1.6861x over previous
//
#include <hip/hip_runtime.h>

#define N_NODES 50000
#define N_EDGES 600000
#define DIN 128
#define HD 128
#define DOUT 64

// ---------------- degree histogram (int) ----------------
__global__ __launch_bounds__(256) void deg_kernel(const int* __restrict__ ei,
                                                  int* __restrict__ degi) {
    int e = blockIdx.x * 256 + threadIdx.x;
    if (e < N_EDGES) {
        int t = ei[N_EDGES + e];  // dst row
        atomicAdd(&degi[t], 1);
    }
}

// ---------------- single-block exclusive scan -> row_ptr, cursor ----------------
__global__ __launch_bounds__(1024) void scan_kernel(const int* __restrict__ degi,
                                                    int* __restrict__ row_ptr,
                                                    int* __restrict__ cursor) {
    __shared__ int wsum[16];
    __shared__ int chunk_carry;
    if (threadIdx.x == 0) chunk_carry = 0;
    __syncthreads();
    const int lane = threadIdx.x & 63;
    const int wid = threadIdx.x >> 6;
    for (int base = 0; base < N_NODES; base += 1024) {
        int i = base + threadIdx.x;
        int v = (i < N_NODES) ? degi[i] : 0;
        int incl = v;
#pragma unroll
        for (int off = 1; off < 64; off <<= 1) {
            int t = __shfl_up(incl, (unsigned)off, 64);
            if (lane >= off) incl += t;
        }
        if (lane == 63) wsum[wid] = incl;
        __syncthreads();
        int waveoff = 0;
        for (int w = 0; w < wid; w++) waveoff += wsum[w];
        int carry = chunk_carry;
        int excl = carry + waveoff + incl - v;
        if (i < N_NODES) { row_ptr[i] = excl; cursor[i] = excl; }
        __syncthreads();
        if (threadIdx.x == 1023) chunk_carry = carry + waveoff + incl;
        __syncthreads();
    }
    if (threadIdx.x == 0) row_ptr[N_NODES] = chunk_carry;
}

// ---------------- CSR fill ----------------
__global__ __launch_bounds__(256) void fill_kernel(const int* __restrict__ ei,
                                                   int* __restrict__ cursor,
                                                   int* __restrict__ csr) {
    int e = blockIdx.x * 256 + threadIdx.x;
    if (e < N_EDGES) {
        int s = ei[e];
        int t = ei[N_EDGES + e];
        int pos = atomicAdd(&cursor[t], 1);
        csr[pos] = s;
    }
}

// ---------------- gather layer-1: mean[n] = sum_{s in N(n)} x[s] / max(deg,1) ----------------
// one wave per node, lane covers dims {lane, lane+64}
__global__ __launch_bounds__(256) void gather1_kernel(const int* __restrict__ row_ptr,
                                                      const int* __restrict__ csr,
                                                      const float* __restrict__ x,
                                                      float* __restrict__ mean) {
    int node = blockIdx.x * 4 + (threadIdx.x >> 6);
    if (node >= N_NODES) return;
    const int lane = threadIdx.x & 63;
    int beg = row_ptr[node], end = row_ptr[node + 1];
    float a0 = 0.f, a1 = 0.f, b0 = 0.f, b1 = 0.f;
    int e = beg;
    for (; e + 1 < end; e += 2) {
        int s0 = csr[e], s1 = csr[e + 1];
        a0 += x[(size_t)s0 * DIN + lane];
        a1 += x[(size_t)s0 * DIN + 64 + lane];
        b0 += x[(size_t)s1 * DIN + lane];
        b1 += x[(size_t)s1 * DIN + 64 + lane];
    }
    if (e < end) {
        int s0 = csr[e];
        a0 += x[(size_t)s0 * DIN + lane];
        a1 += x[(size_t)s0 * DIN + 64 + lane];
    }
    float invd = 1.0f / fmaxf((float)(end - beg), 1.0f);
    mean[(size_t)node * DIN + lane] = (a0 + b0) * invd;
    mean[(size_t)node * DIN + 64 + lane] = (a1 + b1) * invd;
}

// ---------------- layer 1: h = relu(mean@w1l + b1 + x@w1r) ----------------
// block = 256 thr (4 waves), 16 nodes/block, wave handles 4 nodes x 2 cols/lane
// NOTE: h may alias mean — each block stages its 16 mean rows into LDS
// (syncthreads) before writing the same 16 nodes' h rows. No cross-block overlap.
__global__ __launch_bounds__(256) void layer1_kernel(
    const float* __restrict__ x, const float* __restrict__ mean,
    const float* __restrict__ w1l, const float* __restrict__ b1,
    const float* __restrict__ w1r, float* __restrict__ h) {
    __shared__ float sA[16 * DIN];
    __shared__ float sX[16 * DIN];
    const int block0 = blockIdx.x * 16;

    const float4* av = (const float4*)(mean + (size_t)block0 * DIN);
    const float4* xv = (const float4*)(x + (size_t)block0 * DIN);
    float4* sav = (float4*)sA;
    float4* sxv = (float4*)sX;
    for (int i = threadIdx.x; i < 16 * DIN / 4; i += 256) {
        sav[i] = av[i];
        sxv[i] = xv[i];
    }
    __syncthreads();

    const int wave = threadIdx.x >> 6, lane = threadIdx.x & 63;
    const int r0 = wave * 4;
    float aA0[4], aA1[4], aX0[4], aX1[4];
#pragma unroll
    for (int m = 0; m < 4; m++) { aA0[m] = aA1[m] = aX0[m] = aX1[m] = 0.f; }

    for (int k = 0; k < DIN; k++) {
        float wl0 = w1l[k * HD + lane];
        float wl1 = w1l[k * HD + 64 + lane];
        float wr0 = w1r[k * HD + lane];
        float wr1 = w1r[k * HD + 64 + lane];
#pragma unroll
        for (int m = 0; m < 4; m++) {
            float a = sA[(r0 + m) * DIN + k];  // wave-uniform -> LDS broadcast
            float b = sX[(r0 + m) * DIN + k];
            aA0[m] = fmaf(a, wl0, aA0[m]);
            aA1[m] = fmaf(a, wl1, aA1[m]);
            aX0[m] = fmaf(b, wr0, aX0[m]);
            aX1[m] = fmaf(b, wr1, aX1[m]);
        }
    }

    float bb0 = b1[lane], bb1 = b1[64 + lane];
#pragma unroll
    for (int m = 0; m < 4; m++) {
        int node = block0 + r0 + m;
        float v0 = aA0[m] + aX0[m] + bb0;
        float v1 = aA1[m] + aX1[m] + bb1;
        h[(size_t)node * HD + lane] = fmaxf(v0, 0.f);
        h[(size_t)node * HD + 64 + lane] = fmaxf(v1, 0.f);
    }
}

// ---------------- layer-2 pre-transform: p = h@w2l ; out = h@w2r + b2 ----------------
__global__ __launch_bounds__(256) void transform2_kernel(
    const float* __restrict__ h,
    const float* __restrict__ w2l, const float* __restrict__ b2,
    const float* __restrict__ w2r,
    float* __restrict__ p, float* __restrict__ outq) {
    __shared__ float sH[16 * HD];
    const int block0 = blockIdx.x * 16;
    const float4* hv = (const float4*)(h + (size_t)block0 * HD);
    float4* shv = (float4*)sH;
    for (int i = threadIdx.x; i < 16 * HD / 4; i += 256) shv[i] = hv[i];
    __syncthreads();

    const int wave = threadIdx.x >> 6, lane = threadIdx.x & 63;
    const int r0 = wave * 4;
    float aP[4] = {0, 0, 0, 0}, aQ[4] = {0, 0, 0, 0};
    for (int k = 0; k < HD; k++) {
        float wl = w2l[k * DOUT + lane];
        float wr = w2r[k * DOUT + lane];
#pragma unroll
        for (int m = 0; m < 4; m++) {
            float v = sH[(r0 + m) * HD + k];
            aP[m] = fmaf(v, wl, aP[m]);
            aQ[m] = fmaf(v, wr, aQ[m]);
        }
    }
    float bb = b2[lane];
#pragma unroll
    for (int m = 0; m < 4; m++) {
        int node = block0 + r0 + m;
        p[(size_t)node * DOUT + lane] = aP[m];
        outq[(size_t)node * DOUT + lane] = aQ[m] + bb;
    }
}

// ---------------- gather layer-2: out[n] += sum p[s] / max(deg,1) ----------------
__global__ __launch_bounds__(256) void gather2_kernel(const int* __restrict__ row_ptr,
                                                      const int* __restrict__ csr,
                                                      const float* __restrict__ p,
                                                      float* __restrict__ out) {
    int node = blockIdx.x * 4 + (threadIdx.x >> 6);
    if (node >= N_NODES) return;
    const int lane = threadIdx.x & 63;
    int beg = row_ptr[node], end = row_ptr[node + 1];
    float a = 0.f, b = 0.f;
    int e = beg;
    for (; e + 1 < end; e += 2) {
        int s0 = csr[e], s1 = csr[e + 1];
        a += p[(size_t)s0 * DOUT + lane];
        b += p[(size_t)s1 * DOUT + lane];
    }
    if (e < end) {
        a += p[(size_t)csr[e] * DOUT + lane];
    }
    float invd = 1.0f / fmaxf((float)(end - beg), 1.0f);
    out[(size_t)node * DOUT + lane] += (a + b) * invd;
}

extern "C" void kernel_launch(void* const* d_in, const int* in_sizes, int n_in,
                              void* d_out, int out_size, void* d_ws, size_t ws_size,
                              hipStream_t stream) {
    const float* x   = (const float*)d_in[0];
    const int*   ei  = (const int*)d_in[1];   // [2, E] (src row, then dst row)
    const float* w1l = (const float*)d_in[2];
    const float* b1  = (const float*)d_in[3];
    const float* w1r = (const float*)d_in[4];
    const float* w2l = (const float*)d_in[5];
    const float* b2  = (const float*)d_in[6];
    const float* w2r = (const float*)d_in[7];
    float* out = (float*)d_out;

    // workspace layout
    int*   degi    = (int*)d_ws;                       // N
    int*   row_ptr = degi + N_NODES;                   // N+1
    int*   cursor  = row_ptr + N_NODES + 1;            // N
    int*   csr     = cursor + N_NODES;                 // E
    float* mean    = (float*)(csr + N_EDGES);          // N*128  (aliased by h)
    float* h       = mean;                             // N*128  (safe alias, see layer1)
    float* p       = mean + (size_t)N_NODES * DIN;     // N*64
    // total ws use: (3*N+1+E)*4 + (N*128 + N*64)*4 ≈ 41.4 MB

    hipMemsetAsync(degi, 0, N_NODES * sizeof(int), stream);

    deg_kernel<<<(N_EDGES + 255) / 256, 256, 0, stream>>>(ei, degi);
    scan_kernel<<<1, 1024, 0, stream>>>(degi, row_ptr, cursor);
    fill_kernel<<<(N_EDGES + 255) / 256, 256, 0, stream>>>(ei, cursor, csr);

    gather1_kernel<<<(N_NODES + 3) / 4, 256, 0, stream>>>(row_ptr, csr, x, mean);
    layer1_kernel<<<N_NODES / 16, 256, 0, stream>>>(x, mean, w1l, b1, w1r, h);
    transform2_kernel<<<N_NODES / 16, 256, 0, stream>>>(h, w2l, b2, w2r, p, out);
    gather2_kernel<<<(N_NODES + 3) / 4, 256, 0, stream>>>(row_ptr, csr, p, out);
}

// Round 3
// 254.678 us; speedup vs baseline: 2.2493x; 1.3340x over previous
//
#include <hip/hip_runtime.h>

#define N_NODES 50000
#define N_EDGES 600000
#define DIN 128
#define HD 128
#define DOUT 64

typedef float f32x4 __attribute__((ext_vector_type(4)));
typedef short bf16x8 __attribute__((ext_vector_type(8)));

__device__ __forceinline__ unsigned short f2bf(float f) {
    unsigned u = __float_as_uint(f);
    unsigned r = (u + 0x7FFFu + ((u >> 16) & 1u)) >> 16;
    return (unsigned short)r;
}
__device__ __forceinline__ float bf2f(unsigned short s) {
    return __uint_as_float(((unsigned)s) << 16);
}

// ---------------- degree histogram (int) ----------------
__global__ __launch_bounds__(256) void deg_kernel(const int* __restrict__ ei,
                                                  int* __restrict__ degi) {
    int e = blockIdx.x * 256 + threadIdx.x;
    if (e < N_EDGES) atomicAdd(&degi[ei[N_EDGES + e]], 1);
}

// ---------------- single-block exclusive scan -> row_ptr, cursor ----------------
__global__ __launch_bounds__(1024) void scan_kernel(const int* __restrict__ degi,
                                                    int* __restrict__ row_ptr,
                                                    int* __restrict__ cursor) {
    __shared__ int wsum[16];
    __shared__ int chunk_carry;
    if (threadIdx.x == 0) chunk_carry = 0;
    __syncthreads();
    const int lane = threadIdx.x & 63;
    const int wid = threadIdx.x >> 6;
    for (int base = 0; base < N_NODES; base += 1024) {
        int i = base + threadIdx.x;
        int v = (i < N_NODES) ? degi[i] : 0;
        int incl = v;
#pragma unroll
        for (int off = 1; off < 64; off <<= 1) {
            int t = __shfl_up(incl, (unsigned)off, 64);
            if (lane >= off) incl += t;
        }
        if (lane == 63) wsum[wid] = incl;
        __syncthreads();
        int waveoff = 0;
        for (int w = 0; w < wid; w++) waveoff += wsum[w];
        int carry = chunk_carry;
        int excl = carry + waveoff + incl - v;
        if (i < N_NODES) { row_ptr[i] = excl; cursor[i] = excl; }
        __syncthreads();
        if (threadIdx.x == 1023) chunk_carry = carry + waveoff + incl;
        __syncthreads();
    }
    if (threadIdx.x == 0) row_ptr[N_NODES] = chunk_carry;
}

// ---------------- CSR fill ----------------
__global__ __launch_bounds__(256) void fill_kernel(const int* __restrict__ ei,
                                                   int* __restrict__ cursor,
                                                   int* __restrict__ csr) {
    int e = blockIdx.x * 256 + threadIdx.x;
    if (e < N_EDGES) {
        int s = ei[e];
        int t = ei[N_EDGES + e];
        int pos = atomicAdd(&cursor[t], 1);
        csr[pos] = s;
    }
}

// ---------------- gather layer-1: mean[n] = sum x[s] / max(deg,1) ----------------
__global__ __launch_bounds__(256) void gather1_kernel(const int* __restrict__ row_ptr,
                                                      const int* __restrict__ csr,
                                                      const float* __restrict__ x,
                                                      float* __restrict__ mean) {
    int node = blockIdx.x * 4 + (threadIdx.x >> 6);
    if (node >= N_NODES) return;
    const int lane = threadIdx.x & 63;
    int beg = row_ptr[node], end = row_ptr[node + 1];
    float a0 = 0.f, a1 = 0.f, b0 = 0.f, b1 = 0.f;
    int e = beg;
    for (; e + 1 < end; e += 2) {
        int s0 = csr[e], s1 = csr[e + 1];
        a0 += x[(size_t)s0 * DIN + lane];
        a1 += x[(size_t)s0 * DIN + 64 + lane];
        b0 += x[(size_t)s1 * DIN + lane];
        b1 += x[(size_t)s1 * DIN + 64 + lane];
    }
    if (e < end) {
        int s0 = csr[e];
        a0 += x[(size_t)s0 * DIN + lane];
        a1 += x[(size_t)s0 * DIN + 64 + lane];
    }
    float invd = 1.0f / fmaxf((float)(end - beg), 1.0f);
    mean[(size_t)node * DIN + lane] = (a0 + b0) * invd;
    mean[(size_t)node * DIN + 64 + lane] = (a1 + b1) * invd;
}

// ---------------- weight fragment prep (f32 -> bf16 MFMA fragment arrays) ----
// frag array layout: idx = ((ct*4 + kc)*64 + lane)*8 + j
// element = B[kc*32 + (lane>>4)*8 + j][ct*16 + (lane&15)]
// arrays: 0 = w1l [128x128], 1 = w1r [128x128], 2 = [w2l | w2r] [128x128]
__global__ __launch_bounds__(256) void bprep_kernel(const float* __restrict__ w1l,
                                                    const float* __restrict__ w1r,
                                                    const float* __restrict__ w2l,
                                                    const float* __restrict__ w2r,
                                                    unsigned short* __restrict__ bfr) {
    int tid = blockIdx.x * 256 + threadIdx.x;  // < 3*16384
    int a = tid >> 14;
    int r = tid & 16383;
    int j = r & 7, lane = (r >> 3) & 63, kc = (r >> 9) & 3, ct = r >> 11;
    int k = kc * 32 + ((lane >> 4) << 3) + j;
    int c = (ct << 4) + (lane & 15);
    float v;
    if (a == 0) v = w1l[k * HD + c];
    else if (a == 1) v = w1r[k * HD + c];
    else v = (c < 64) ? w2l[k * DOUT + c] : w2r[k * DOUT + (c - 64)];
    bfr[tid] = f2bf(v);
}

// ---------------- fused MFMA: h=relu(mean@w1l + x@w1r + b1); p=h@w2l; out=h@w2r+b2
// block = 256 thr (4 waves), BM=64 rows, BN=128 cols, 16x16x32 bf16 MFMA,
// A = hi+lo bf16 split (2 MFMA per B-frag). A staged in LDS with
// byte ^= (row&7)<<4 swizzle; B read as per-lane-contiguous fragments from global.
__global__ __launch_bounds__(256) void fused_kernel(
    const float* __restrict__ mean, const float* __restrict__ x,
    const unsigned short* __restrict__ B1a, const unsigned short* __restrict__ B1b,
    const unsigned short* __restrict__ B2,
    const float* __restrict__ b1, const float* __restrict__ b2,
    float* __restrict__ p, float* __restrict__ out) {
    __shared__ unsigned short Ahi[64 * 128];
    __shared__ unsigned short Alo[64 * 128];
    const int block0 = blockIdx.x * 64;
    const int lane = threadIdx.x & 63;
    const int wtile = threadIdx.x >> 6;

    f32x4 acc[8];
#pragma unroll
    for (int t = 0; t < 8; t++) acc[t] = (f32x4){0.f, 0.f, 0.f, 0.f};

    auto stage = [&](const float* __restrict__ S) {
#pragma unroll
        for (int i = 0; i < 8; i++) {
            int f = threadIdx.x + i * 256;
            int row = f >> 5;   // 32 float4 per 128-wide row
            int c4 = f & 31;
            int rg = block0 + row;
            if (rg >= N_NODES) rg = N_NODES - 1;
            float4 v = *(const float4*)(S + (size_t)rg * 128 + c4 * 4);
            ushort4 hi, lo;
            hi.x = f2bf(v.x); lo.x = f2bf(v.x - bf2f(hi.x));
            hi.y = f2bf(v.y); lo.y = f2bf(v.y - bf2f(hi.y));
            hi.z = f2bf(v.z); lo.z = f2bf(v.z - bf2f(hi.z));
            hi.w = f2bf(v.w); lo.w = f2bf(v.w - bf2f(hi.w));
            int byte = row * 256 + ((c4 * 8) ^ ((row & 7) << 4));
            *(ushort4*)((char*)Ahi + byte) = hi;
            *(ushort4*)((char*)Alo + byte) = lo;
        }
    };

    auto compute = [&](const unsigned short* __restrict__ Bf) {
        const int arow = wtile * 16 + (lane & 15);
        const int swz = (arow & 7) << 4;
#pragma unroll
        for (int kc = 0; kc < 4; kc++) {
            int byte = arow * 256 + ((kc * 64 + ((lane >> 4) << 4)) ^ swz);
            bf16x8 ahi = *(const bf16x8*)((const char*)Ahi + byte);
            bf16x8 alo = *(const bf16x8*)((const char*)Alo + byte);
#pragma unroll
            for (int ct = 0; ct < 8; ct++) {
                bf16x8 b = *(const bf16x8*)(Bf + ((((ct << 2) + kc) << 6) + lane) * 8);
                acc[ct] = __builtin_amdgcn_mfma_f32_16x16x32_bf16(ahi, b, acc[ct], 0, 0, 0);
                acc[ct] = __builtin_amdgcn_mfma_f32_16x16x32_bf16(alo, b, acc[ct], 0, 0, 0);
            }
        }
    };

    stage(mean);
    __syncthreads();
    compute(B1a);
    __syncthreads();
    stage(x);
    __syncthreads();
    compute(B1b);
    __syncthreads();

    // epilogue 1: h = relu(acc + b1) -> restage as bf16 hi/lo A-tile (k = col)
    {
        const int r0 = wtile * 16 + ((lane >> 4) << 2);
#pragma unroll
        for (int ct = 0; ct < 8; ct++) {
            int col = (ct << 4) + (lane & 15);
            float bv = b1[col];
#pragma unroll
            for (int r = 0; r < 4; r++) {
                float v = fmaxf(acc[ct][r] + bv, 0.f);
                unsigned short hi = f2bf(v);
                unsigned short lo = f2bf(v - bf2f(hi));
                int row = r0 + r;
                int byte = row * 256 + ((col * 2) ^ ((row & 7) << 4));
                *(unsigned short*)((char*)Ahi + byte) = hi;
                *(unsigned short*)((char*)Alo + byte) = lo;
            }
            acc[ct] = (f32x4){0.f, 0.f, 0.f, 0.f};
        }
    }
    __syncthreads();
    compute(B2);

    // epilogue 2: cols 0-63 -> p, cols 64-127 -> out (+b2)
    {
        const int r0 = wtile * 16 + ((lane >> 4) << 2);
#pragma unroll
        for (int ct = 0; ct < 8; ct++) {
            int col = (ct << 4) + (lane & 15);
#pragma unroll
            for (int r = 0; r < 4; r++) {
                int node = block0 + r0 + r;
                if (node < N_NODES) {
                    if (ct < 4) p[(size_t)node * DOUT + col] = acc[ct][r];
                    else out[(size_t)node * DOUT + (col - 64)] = acc[ct][r] + b2[col - 64];
                }
            }
        }
    }
}

// ---------------- gather layer-2: out[n] += sum p[s] / max(deg,1) ----------------
__global__ __launch_bounds__(256) void gather2_kernel(const int* __restrict__ row_ptr,
                                                      const int* __restrict__ csr,
                                                      const float* __restrict__ p,
                                                      float* __restrict__ out) {
    int node = blockIdx.x * 4 + (threadIdx.x >> 6);
    if (node >= N_NODES) return;
    const int lane = threadIdx.x & 63;
    int beg = row_ptr[node], end = row_ptr[node + 1];
    float a = 0.f, b = 0.f;
    int e = beg;
    for (; e + 1 < end; e += 2) {
        int s0 = csr[e], s1 = csr[e + 1];
        a += p[(size_t)s0 * DOUT + lane];
        b += p[(size_t)s1 * DOUT + lane];
    }
    if (e < end) a += p[(size_t)csr[e] * DOUT + lane];
    float invd = 1.0f / fmaxf((float)(end - beg), 1.0f);
    out[(size_t)node * DOUT + lane] += (a + b) * invd;
}

extern "C" void kernel_launch(void* const* d_in, const int* in_sizes, int n_in,
                              void* d_out, int out_size, void* d_ws, size_t ws_size,
                              hipStream_t stream) {
    const float* x   = (const float*)d_in[0];
    const int*   ei  = (const int*)d_in[1];
    const float* w1l = (const float*)d_in[2];
    const float* b1  = (const float*)d_in[3];
    const float* w1r = (const float*)d_in[4];
    const float* w2l = (const float*)d_in[5];
    const float* b2  = (const float*)d_in[6];
    const float* w2r = (const float*)d_in[7];
    float* out = (float*)d_out;

    // workspace layout (int offsets; float regions 16B-aligned)
    int* iw = (int*)d_ws;
    int* degi    = iw;                       // 50000
    int* row_ptr = iw + 50000;               // 50001
    int* cursor  = iw + 100001;              // 50000
    int* csr     = iw + 150001;              // 600000  (ends at 750001)
    float* mean  = (float*)(iw + 750016);    // N*128, 16B aligned
    float* p     = mean + (size_t)N_NODES * DIN;   // N*64
    unsigned short* bfr = (unsigned short*)(p + (size_t)N_NODES * DOUT);  // 3*16384
    const unsigned short* B1a = bfr;
    const unsigned short* B1b = bfr + 16384;
    const unsigned short* B2  = bfr + 32768;
    // total ws use ~= 41.5 MB

    hipMemsetAsync(degi, 0, N_NODES * sizeof(int), stream);

    bprep_kernel<<<192, 256, 0, stream>>>(w1l, w1r, w2l, w2r, bfr);
    deg_kernel<<<(N_EDGES + 255) / 256, 256, 0, stream>>>(ei, degi);
    scan_kernel<<<1, 1024, 0, stream>>>(degi, row_ptr, cursor);
    fill_kernel<<<(N_EDGES + 255) / 256, 256, 0, stream>>>(ei, cursor, csr);

    gather1_kernel<<<(N_NODES + 3) / 4, 256, 0, stream>>>(row_ptr, csr, x, mean);
    fused_kernel<<<(N_NODES + 63) / 64, 256, 0, stream>>>(mean, x, B1a, B1b, B2,
                                                          b1, b2, p, out);
    gather2_kernel<<<(N_NODES + 3) / 4, 256, 0, stream>>>(row_ptr, csr, p, out);
}

// Round 4
// 211.497 us; speedup vs baseline: 2.7085x; 1.2042x over previous
//
#include <hip/hip_runtime.h>

#define N_NODES 50000
#define N_EDGES 600000
#define DIN 128
#define HD 128
#define DOUT 64
#define SCAN_BLOCKS 196  // ceil(50000/256)

typedef float f32x4 __attribute__((ext_vector_type(4)));
typedef short bf16x8 __attribute__((ext_vector_type(8)));

__device__ __forceinline__ unsigned short f2bf(float f) {
    unsigned u = __float_as_uint(f);
    unsigned r = (u + 0x7FFFu + ((u >> 16) & 1u)) >> 16;
    return (unsigned short)r;
}
__device__ __forceinline__ float bf2f(unsigned short s) {
    return __uint_as_float(((unsigned)s) << 16);
}

// ---------------- degree histogram (int) ----------------
__global__ __launch_bounds__(256) void deg_kernel(const int* __restrict__ ei,
                                                  int* __restrict__ degi) {
    int e = blockIdx.x * 256 + threadIdx.x;
    if (e < N_EDGES) atomicAdd(&degi[ei[N_EDGES + e]], 1);
}

// ---------------- scan phase A: per-block (256-elem) sums ----------------
__global__ __launch_bounds__(256) void scanA_kernel(const int* __restrict__ degi,
                                                    int* __restrict__ partial) {
    int i = blockIdx.x * 256 + threadIdx.x;
    int v = (i < N_NODES) ? degi[i] : 0;
#pragma unroll
    for (int off = 32; off > 0; off >>= 1) v += __shfl_down(v, (unsigned)off, 64);
    __shared__ int ws[4];
    const int lane = threadIdx.x & 63, wid = threadIdx.x >> 6;
    if (lane == 0) ws[wid] = v;
    __syncthreads();
    if (threadIdx.x == 0) partial[blockIdx.x] = ws[0] + ws[1] + ws[2] + ws[3];
}

// ---------------- scan phase B: 1 block scans the partials (exclusive, in place) ---
__global__ __launch_bounds__(256) void scanB_kernel(int* __restrict__ partial,
                                                    int* __restrict__ row_ptr) {
    const int lane = threadIdx.x & 63, wid = threadIdx.x >> 6;
    int i = threadIdx.x;
    int v = (i < SCAN_BLOCKS) ? partial[i] : 0;
    int incl = v;
#pragma unroll
    for (int off = 1; off < 64; off <<= 1) {
        int t = __shfl_up(incl, (unsigned)off, 64);
        if (lane >= off) incl += t;
    }
    __shared__ int ws[4];
    if (lane == 63) ws[wid] = incl;
    __syncthreads();
    int woff = 0;
    for (int w = 0; w < wid; w++) woff += ws[w];
    incl += woff;
    if (i < SCAN_BLOCKS) partial[i] = incl - v;   // exclusive block offset
    if (i == 255) row_ptr[N_NODES] = incl;        // total = E
}

// ---------------- scan phase C: local scan + block offset -> row_ptr, cursor -----
__global__ __launch_bounds__(256) void scanC_kernel(const int* __restrict__ degi,
                                                    const int* __restrict__ partial,
                                                    int* __restrict__ row_ptr,
                                                    int* __restrict__ cursor) {
    const int lane = threadIdx.x & 63, wid = threadIdx.x >> 6;
    int i = blockIdx.x * 256 + threadIdx.x;
    int v = (i < N_NODES) ? degi[i] : 0;
    int incl = v;
#pragma unroll
    for (int off = 1; off < 64; off <<= 1) {
        int t = __shfl_up(incl, (unsigned)off, 64);
        if (lane >= off) incl += t;
    }
    __shared__ int ws[4];
    if (lane == 63) ws[wid] = incl;
    __syncthreads();
    int woff = 0;
    for (int w = 0; w < wid; w++) woff += ws[w];
    int excl = partial[blockIdx.x] + woff + incl - v;
    if (i < N_NODES) { row_ptr[i] = excl; cursor[i] = excl; }
}

// ---------------- CSR fill ----------------
__global__ __launch_bounds__(256) void fill_kernel(const int* __restrict__ ei,
                                                   int* __restrict__ cursor,
                                                   int* __restrict__ csr) {
    int e = blockIdx.x * 256 + threadIdx.x;
    if (e < N_EDGES) {
        int s = ei[e];
        int t = ei[N_EDGES + e];
        int pos = atomicAdd(&cursor[t], 1);
        csr[pos] = s;
    }
}

// ---------------- x -> bf16 ----------------
__global__ __launch_bounds__(256) void xcvt_kernel(const float* __restrict__ x,
                                                   unsigned short* __restrict__ xb) {
    int i = blockIdx.x * 256 + threadIdx.x;  // < N*128/4 (exact)
    float4 v = ((const float4*)x)[i];
    ushort4 o;
    o.x = f2bf(v.x); o.y = f2bf(v.y); o.z = f2bf(v.z); o.w = f2bf(v.w);
    ((ushort4*)xb)[i] = o;
}

// ---------------- gather layer-1 (bf16 payload): mean[n] = sum xb[s] / max(deg,1)
// one wave per node, lane covers dims {2*lane, 2*lane+1} (packed bf16x2 loads)
__global__ __launch_bounds__(256) void gather1_kernel(const int* __restrict__ row_ptr,
                                                      const int* __restrict__ csr,
                                                      const unsigned short* __restrict__ xb,
                                                      float* __restrict__ mean) {
    int node = blockIdx.x * 4 + (threadIdx.x >> 6);
    if (node >= N_NODES) return;
    const int lane = threadIdx.x & 63;
    int beg = row_ptr[node], end = row_ptr[node + 1];
    float a0 = 0.f, a1 = 0.f, b0 = 0.f, b1 = 0.f;
    int e = beg;
    for (; e + 1 < end; e += 2) {
        int s0 = csr[e], s1 = csr[e + 1];
        unsigned u0 = *(const unsigned*)(xb + (size_t)s0 * DIN + lane * 2);
        unsigned u1 = *(const unsigned*)(xb + (size_t)s1 * DIN + lane * 2);
        a0 += __uint_as_float(u0 << 16);
        a1 += __uint_as_float(u0 & 0xffff0000u);
        b0 += __uint_as_float(u1 << 16);
        b1 += __uint_as_float(u1 & 0xffff0000u);
    }
    if (e < end) {
        unsigned u0 = *(const unsigned*)(xb + (size_t)csr[e] * DIN + lane * 2);
        a0 += __uint_as_float(u0 << 16);
        a1 += __uint_as_float(u0 & 0xffff0000u);
    }
    float invd = 1.0f / fmaxf((float)(end - beg), 1.0f);
    float2 r;
    r.x = (a0 + b0) * invd;
    r.y = (a1 + b1) * invd;
    *(float2*)(mean + (size_t)node * DIN + lane * 2) = r;
}

// ---------------- weight fragment prep (f32 -> bf16 MFMA fragment arrays) ----
// frag array layout: idx = ((ct*4 + kc)*64 + lane)*8 + j
// element = B[kc*32 + (lane>>4)*8 + j][ct*16 + (lane&15)]
__global__ __launch_bounds__(256) void bprep_kernel(const float* __restrict__ w1l,
                                                    const float* __restrict__ w1r,
                                                    const float* __restrict__ w2l,
                                                    const float* __restrict__ w2r,
                                                    unsigned short* __restrict__ bfr) {
    int tid = blockIdx.x * 256 + threadIdx.x;  // < 3*16384
    int a = tid >> 14;
    int r = tid & 16383;
    int j = r & 7, lane = (r >> 3) & 63, kc = (r >> 9) & 3, ct = r >> 11;
    int k = kc * 32 + ((lane >> 4) << 3) + j;
    int c = (ct << 4) + (lane & 15);
    float v;
    if (a == 0) v = w1l[k * HD + c];
    else if (a == 1) v = w1r[k * HD + c];
    else v = (c < 64) ? w2l[k * DOUT + c] : w2r[k * DOUT + (c - 64)];
    bfr[tid] = f2bf(v);
}

// ---------------- fused MFMA: h=relu(mean@w1l + x@w1r + b1); p=h@w2l; out=h@w2r+b2
__global__ __launch_bounds__(256) void fused_kernel(
    const float* __restrict__ mean, const float* __restrict__ x,
    const unsigned short* __restrict__ B1a, const unsigned short* __restrict__ B1b,
    const unsigned short* __restrict__ B2,
    const float* __restrict__ b1, const float* __restrict__ b2,
    unsigned short* __restrict__ pb, float* __restrict__ out) {
    __shared__ unsigned short Ahi[64 * 128];
    __shared__ unsigned short Alo[64 * 128];
    const int block0 = blockIdx.x * 64;
    const int lane = threadIdx.x & 63;
    const int wtile = threadIdx.x >> 6;

    f32x4 acc[8];
#pragma unroll
    for (int t = 0; t < 8; t++) acc[t] = (f32x4){0.f, 0.f, 0.f, 0.f};

    auto stage = [&](const float* __restrict__ S) {
#pragma unroll
        for (int i = 0; i < 8; i++) {
            int f = threadIdx.x + i * 256;
            int row = f >> 5;
            int c4 = f & 31;
            int rg = block0 + row;
            if (rg >= N_NODES) rg = N_NODES - 1;
            float4 v = *(const float4*)(S + (size_t)rg * 128 + c4 * 4);
            ushort4 hi, lo;
            hi.x = f2bf(v.x); lo.x = f2bf(v.x - bf2f(hi.x));
            hi.y = f2bf(v.y); lo.y = f2bf(v.y - bf2f(hi.y));
            hi.z = f2bf(v.z); lo.z = f2bf(v.z - bf2f(hi.z));
            hi.w = f2bf(v.w); lo.w = f2bf(v.w - bf2f(hi.w));
            int byte = row * 256 + ((c4 * 8) ^ ((row & 7) << 4));
            *(ushort4*)((char*)Ahi + byte) = hi;
            *(ushort4*)((char*)Alo + byte) = lo;
        }
    };

    auto compute = [&](const unsigned short* __restrict__ Bf) {
        const int arow = wtile * 16 + (lane & 15);
        const int swz = (arow & 7) << 4;
#pragma unroll
        for (int kc = 0; kc < 4; kc++) {
            int byte = arow * 256 + ((kc * 64 + ((lane >> 4) << 4)) ^ swz);
            bf16x8 ahi = *(const bf16x8*)((const char*)Ahi + byte);
            bf16x8 alo = *(const bf16x8*)((const char*)Alo + byte);
#pragma unroll
            for (int ct = 0; ct < 8; ct++) {
                bf16x8 b = *(const bf16x8*)(Bf + ((((ct << 2) + kc) << 6) + lane) * 8);
                acc[ct] = __builtin_amdgcn_mfma_f32_16x16x32_bf16(ahi, b, acc[ct], 0, 0, 0);
                acc[ct] = __builtin_amdgcn_mfma_f32_16x16x32_bf16(alo, b, acc[ct], 0, 0, 0);
            }
        }
    };

    stage(mean);
    __syncthreads();
    compute(B1a);
    __syncthreads();
    stage(x);
    __syncthreads();
    compute(B1b);
    __syncthreads();

    // epilogue 1: h = relu(acc + b1) -> restage as bf16 hi/lo A-tile (k = col)
    {
        const int r0 = wtile * 16 + ((lane >> 4) << 2);
#pragma unroll
        for (int ct = 0; ct < 8; ct++) {
            int col = (ct << 4) + (lane & 15);
            float bv = b1[col];
#pragma unroll
            for (int r = 0; r < 4; r++) {
                float v = fmaxf(acc[ct][r] + bv, 0.f);
                unsigned short hi = f2bf(v);
                unsigned short lo = f2bf(v - bf2f(hi));
                int row = r0 + r;
                int byte = row * 256 + ((col * 2) ^ ((row & 7) << 4));
                *(unsigned short*)((char*)Ahi + byte) = hi;
                *(unsigned short*)((char*)Alo + byte) = lo;
            }
            acc[ct] = (f32x4){0.f, 0.f, 0.f, 0.f};
        }
    }
    __syncthreads();
    compute(B2);

    // epilogue 2: cols 0-63 -> pb (bf16), cols 64-127 -> out (+b2, f32)
    {
        const int r0 = wtile * 16 + ((lane >> 4) << 2);
#pragma unroll
        for (int ct = 0; ct < 8; ct++) {
            int col = (ct << 4) + (lane & 15);
#pragma unroll
            for (int r = 0; r < 4; r++) {
                int node = block0 + r0 + r;
                if (node < N_NODES) {
                    if (ct < 4) pb[(size_t)node * DOUT + col] = f2bf(acc[ct][r]);
                    else out[(size_t)node * DOUT + (col - 64)] = acc[ct][r] + b2[col - 64];
                }
            }
        }
    }
}

// ---------------- gather layer-2 (bf16 payload): out[n] += sum pb[s] / max(deg,1)
__global__ __launch_bounds__(256) void gather2_kernel(const int* __restrict__ row_ptr,
                                                      const int* __restrict__ csr,
                                                      const unsigned short* __restrict__ pb,
                                                      float* __restrict__ out) {
    int node = blockIdx.x * 4 + (threadIdx.x >> 6);
    if (node >= N_NODES) return;
    const int lane = threadIdx.x & 63;
    int beg = row_ptr[node], end = row_ptr[node + 1];
    float a = 0.f, b = 0.f;
    int e = beg;
    for (; e + 1 < end; e += 2) {
        int s0 = csr[e], s1 = csr[e + 1];
        a += bf2f(pb[(size_t)s0 * DOUT + lane]);
        b += bf2f(pb[(size_t)s1 * DOUT + lane]);
    }
    if (e < end) a += bf2f(pb[(size_t)csr[e] * DOUT + lane]);
    float invd = 1.0f / fmaxf((float)(end - beg), 1.0f);
    out[(size_t)node * DOUT + lane] += (a + b) * invd;
}

extern "C" void kernel_launch(void* const* d_in, const int* in_sizes, int n_in,
                              void* d_out, int out_size, void* d_ws, size_t ws_size,
                              hipStream_t stream) {
    const float* x   = (const float*)d_in[0];
    const int*   ei  = (const int*)d_in[1];
    const float* w1l = (const float*)d_in[2];
    const float* b1  = (const float*)d_in[3];
    const float* w1r = (const float*)d_in[4];
    const float* w2l = (const float*)d_in[5];
    const float* b2  = (const float*)d_in[6];
    const float* w2r = (const float*)d_in[7];
    float* out = (float*)d_out;

    // workspace layout
    int* iw = (int*)d_ws;
    int* degi    = iw;                        // 50000
    int* row_ptr = iw + 50000;                // 50001
    int* cursor  = iw + 100001;               // 50000
    int* csr     = iw + 150001;               // 600000
    int* partial = iw + 750001;               // 256   (ends 750257)
    float* mean  = (float*)(iw + 750272);     // N*128 f32, 16B aligned
    unsigned short* xb  = (unsigned short*)(mean + (size_t)N_NODES * DIN);  // N*128 bf16
    unsigned short* pbb = xb + (size_t)N_NODES * DIN;                       // N*64 bf16
    unsigned short* bfr = pbb + (size_t)N_NODES * DOUT;                     // 3*16384 bf16
    const unsigned short* B1a = bfr;
    const unsigned short* B1b = bfr + 16384;
    const unsigned short* B2  = bfr + 32768;
    // total ws use ~= 47.9 MB

    hipMemsetAsync(degi, 0, N_NODES * sizeof(int), stream);

    bprep_kernel<<<192, 256, 0, stream>>>(w1l, w1r, w2l, w2r, bfr);
    xcvt_kernel<<<(N_NODES * DIN / 4) / 256, 256, 0, stream>>>(x, xb);
    deg_kernel<<<(N_EDGES + 255) / 256, 256, 0, stream>>>(ei, degi);
    scanA_kernel<<<SCAN_BLOCKS, 256, 0, stream>>>(degi, partial);
    scanB_kernel<<<1, 256, 0, stream>>>(partial, row_ptr);
    scanC_kernel<<<SCAN_BLOCKS, 256, 0, stream>>>(degi, partial, row_ptr, cursor);
    fill_kernel<<<(N_EDGES + 255) / 256, 256, 0, stream>>>(ei, cursor, csr);

    gather1_kernel<<<(N_NODES + 3) / 4, 256, 0, stream>>>(row_ptr, csr, xb, mean);
    fused_kernel<<<(N_NODES + 63) / 64, 256, 0, stream>>>(mean, x, B1a, B1b, B2,
                                                          b1, b2, pbb, out);
    gather2_kernel<<<(N_NODES + 3) / 4, 256, 0, stream>>>(row_ptr, csr, pbb, out);
}

// Round 5
// 175.806 us; speedup vs baseline: 3.2584x; 1.2030x over previous
//
#include <hip/hip_runtime.h>

#define N_NODES 50000
#define N_EDGES 600000
#define DIN 128
#define HD 128
#define DOUT 64
#define SCAN_BLOCKS 196  // ceil(50000/256)

typedef float f32x4 __attribute__((ext_vector_type(4)));
typedef short bf16x8 __attribute__((ext_vector_type(8)));

__device__ __forceinline__ unsigned short f2bf(float f) {
    unsigned u = __float_as_uint(f);
    unsigned r = (u + 0x7FFFu + ((u >> 16) & 1u)) >> 16;
    return (unsigned short)r;
}
__device__ __forceinline__ float bf2f(unsigned short s) {
    return __uint_as_float(((unsigned)s) << 16);
}

// ---------------- degree histogram (int) ----------------
__global__ __launch_bounds__(256) void deg_kernel(const int* __restrict__ ei,
                                                  int* __restrict__ degi) {
    int e = blockIdx.x * 256 + threadIdx.x;
    if (e < N_EDGES) atomicAdd(&degi[ei[N_EDGES + e]], 1);
}

// ---------------- scan phase A: per-block (256-elem) sums ----------------
__global__ __launch_bounds__(256) void scanA_kernel(const int* __restrict__ degi,
                                                    int* __restrict__ partial) {
    int i = blockIdx.x * 256 + threadIdx.x;
    int v = (i < N_NODES) ? degi[i] : 0;
#pragma unroll
    for (int off = 32; off > 0; off >>= 1) v += __shfl_down(v, (unsigned)off, 64);
    __shared__ int ws[4];
    const int lane = threadIdx.x & 63, wid = threadIdx.x >> 6;
    if (lane == 0) ws[wid] = v;
    __syncthreads();
    if (threadIdx.x == 0) partial[blockIdx.x] = ws[0] + ws[1] + ws[2] + ws[3];
}

// ---------------- scan phase B: 1 block scans the partials ----------------
__global__ __launch_bounds__(256) void scanB_kernel(int* __restrict__ partial,
                                                    int* __restrict__ row_ptr) {
    const int lane = threadIdx.x & 63, wid = threadIdx.x >> 6;
    int i = threadIdx.x;
    int v = (i < SCAN_BLOCKS) ? partial[i] : 0;
    int incl = v;
#pragma unroll
    for (int off = 1; off < 64; off <<= 1) {
        int t = __shfl_up(incl, (unsigned)off, 64);
        if (lane >= off) incl += t;
    }
    __shared__ int ws[4];
    if (lane == 63) ws[wid] = incl;
    __syncthreads();
    int woff = 0;
    for (int w = 0; w < wid; w++) woff += ws[w];
    incl += woff;
    if (i < SCAN_BLOCKS) partial[i] = incl - v;
    if (i == 255) row_ptr[N_NODES] = incl;
}

// ---------------- scan phase C: local scan + block offset ----------------
__global__ __launch_bounds__(256) void scanC_kernel(const int* __restrict__ degi,
                                                    const int* __restrict__ partial,
                                                    int* __restrict__ row_ptr,
                                                    int* __restrict__ cursor) {
    const int lane = threadIdx.x & 63, wid = threadIdx.x >> 6;
    int i = blockIdx.x * 256 + threadIdx.x;
    int v = (i < N_NODES) ? degi[i] : 0;
    int incl = v;
#pragma unroll
    for (int off = 1; off < 64; off <<= 1) {
        int t = __shfl_up(incl, (unsigned)off, 64);
        if (lane >= off) incl += t;
    }
    __shared__ int ws[4];
    if (lane == 63) ws[wid] = incl;
    __syncthreads();
    int woff = 0;
    for (int w = 0; w < wid; w++) woff += ws[w];
    int excl = partial[blockIdx.x] + woff + incl - v;
    if (i < N_NODES) { row_ptr[i] = excl; cursor[i] = excl; }
}

// ---------------- CSR fill ----------------
__global__ __launch_bounds__(256) void fill_kernel(const int* __restrict__ ei,
                                                   int* __restrict__ cursor,
                                                   int* __restrict__ csr) {
    int e = blockIdx.x * 256 + threadIdx.x;
    if (e < N_EDGES) {
        int s = ei[e];
        int t = ei[N_EDGES + e];
        int pos = atomicAdd(&cursor[t], 1);
        csr[pos] = s;
    }
}

// ---------------- x -> bf16 ----------------
__global__ __launch_bounds__(256) void xcvt_kernel(const float* __restrict__ x,
                                                   unsigned short* __restrict__ xb) {
    int i = blockIdx.x * 256 + threadIdx.x;
    float4 v = ((const float4*)x)[i];
    ushort4 o;
    o.x = f2bf(v.x); o.y = f2bf(v.y); o.z = f2bf(v.z); o.w = f2bf(v.w);
    ((ushort4*)xb)[i] = o;
}

// ---------------- gather layer-1 (wide): 4 edges/wave, 16 lanes x 8 dims ------
__global__ __launch_bounds__(256) void gather1_kernel(const int* __restrict__ row_ptr,
                                                      const int* __restrict__ csr,
                                                      const unsigned short* __restrict__ xb,
                                                      float* __restrict__ mean) {
    int node = blockIdx.x * 4 + (threadIdx.x >> 6);
    if (node >= N_NODES) return;
    const int lane = threadIdx.x & 63;
    const int g = lane >> 4;   // edge slot 0..3
    const int sl = lane & 15;  // dim block: dims [8*sl, 8*sl+8)
    int beg = row_ptr[node], end = row_ptr[node + 1];
    float acc[8] = {0.f, 0.f, 0.f, 0.f, 0.f, 0.f, 0.f, 0.f};
    for (int base = beg + g; base < end; base += 4) {
        int s = csr[base];
        uint4 u = *(const uint4*)(xb + (size_t)s * DIN + sl * 8);
        acc[0] += __uint_as_float(u.x << 16);
        acc[1] += __uint_as_float(u.x & 0xffff0000u);
        acc[2] += __uint_as_float(u.y << 16);
        acc[3] += __uint_as_float(u.y & 0xffff0000u);
        acc[4] += __uint_as_float(u.z << 16);
        acc[5] += __uint_as_float(u.z & 0xffff0000u);
        acc[6] += __uint_as_float(u.w << 16);
        acc[7] += __uint_as_float(u.w & 0xffff0000u);
    }
#pragma unroll
    for (int i = 0; i < 8; i++) {
        acc[i] += __shfl_xor(acc[i], 16, 64);
        acc[i] += __shfl_xor(acc[i], 32, 64);
    }
    // lane (g,sl) writes dims {8*sl + 2*g, 8*sl + 2*g + 1}  (static-index select)
    float r0, r1;
    if (g == 0)      { r0 = acc[0]; r1 = acc[1]; }
    else if (g == 1) { r0 = acc[2]; r1 = acc[3]; }
    else if (g == 2) { r0 = acc[4]; r1 = acc[5]; }
    else             { r0 = acc[6]; r1 = acc[7]; }
    float invd = 1.0f / fmaxf((float)(end - beg), 1.0f);
    float2 r; r.x = r0 * invd; r.y = r1 * invd;
    *(float2*)(mean + (size_t)node * DIN + sl * 8 + g * 2) = r;
}

// ---------------- weight fragment prep (f32 -> bf16 MFMA fragment arrays) ----
__global__ __launch_bounds__(256) void bprep_kernel(const float* __restrict__ w1l,
                                                    const float* __restrict__ w1r,
                                                    const float* __restrict__ w2l,
                                                    const float* __restrict__ w2r,
                                                    unsigned short* __restrict__ bfr) {
    int tid = blockIdx.x * 256 + threadIdx.x;  // < 3*16384
    int a = tid >> 14;
    int r = tid & 16383;
    int j = r & 7, lane = (r >> 3) & 63, kc = (r >> 9) & 3, ct = r >> 11;
    int k = kc * 32 + ((lane >> 4) << 3) + j;
    int c = (ct << 4) + (lane & 15);
    float v;
    if (a == 0) v = w1l[k * HD + c];
    else if (a == 1) v = w1r[k * HD + c];
    else v = (c < 64) ? w2l[k * DOUT + c] : w2r[k * DOUT + (c - 64)];
    bfr[tid] = f2bf(v);
}

// ---------------- fused MFMA: h=relu(mean@w1l + x@w1r + b1); p=h@w2l; out=h@w2r+b2
__global__ __launch_bounds__(256) void fused_kernel(
    const float* __restrict__ mean, const float* __restrict__ x,
    const unsigned short* __restrict__ B1a, const unsigned short* __restrict__ B1b,
    const unsigned short* __restrict__ B2,
    const float* __restrict__ b1, const float* __restrict__ b2,
    unsigned short* __restrict__ pb, float* __restrict__ out) {
    __shared__ unsigned short Ahi[64 * 128];
    __shared__ unsigned short Alo[64 * 128];
    const int block0 = blockIdx.x * 64;
    const int lane = threadIdx.x & 63;
    const int wtile = threadIdx.x >> 6;

    f32x4 acc[8];
#pragma unroll
    for (int t = 0; t < 8; t++) acc[t] = (f32x4){0.f, 0.f, 0.f, 0.f};

    auto stage = [&](const float* __restrict__ S) {
#pragma unroll
        for (int i = 0; i < 8; i++) {
            int f = threadIdx.x + i * 256;
            int row = f >> 5;
            int c4 = f & 31;
            int rg = block0 + row;
            if (rg >= N_NODES) rg = N_NODES - 1;
            float4 v = *(const float4*)(S + (size_t)rg * 128 + c4 * 4);
            ushort4 hi, lo;
            hi.x = f2bf(v.x); lo.x = f2bf(v.x - bf2f(hi.x));
            hi.y = f2bf(v.y); lo.y = f2bf(v.y - bf2f(hi.y));
            hi.z = f2bf(v.z); lo.z = f2bf(v.z - bf2f(hi.z));
            hi.w = f2bf(v.w); lo.w = f2bf(v.w - bf2f(hi.w));
            int byte = row * 256 + ((c4 * 8) ^ ((row & 7) << 4));
            *(ushort4*)((char*)Ahi + byte) = hi;
            *(ushort4*)((char*)Alo + byte) = lo;
        }
    };

    auto compute = [&](const unsigned short* __restrict__ Bf) {
        const int arow = wtile * 16 + (lane & 15);
        const int swz = (arow & 7) << 4;
#pragma unroll
        for (int kc = 0; kc < 4; kc++) {
            int byte = arow * 256 + ((kc * 64 + ((lane >> 4) << 4)) ^ swz);
            bf16x8 ahi = *(const bf16x8*)((const char*)Ahi + byte);
            bf16x8 alo = *(const bf16x8*)((const char*)Alo + byte);
#pragma unroll
            for (int ct = 0; ct < 8; ct++) {
                bf16x8 b = *(const bf16x8*)(Bf + ((((ct << 2) + kc) << 6) + lane) * 8);
                acc[ct] = __builtin_amdgcn_mfma_f32_16x16x32_bf16(ahi, b, acc[ct], 0, 0, 0);
                acc[ct] = __builtin_amdgcn_mfma_f32_16x16x32_bf16(alo, b, acc[ct], 0, 0, 0);
            }
        }
    };

    stage(mean);
    __syncthreads();
    compute(B1a);
    __syncthreads();
    stage(x);
    __syncthreads();
    compute(B1b);
    __syncthreads();

    // epilogue 1: h = relu(acc + b1) -> restage as bf16 hi/lo A-tile
    {
        const int r0 = wtile * 16 + ((lane >> 4) << 2);
#pragma unroll
        for (int ct = 0; ct < 8; ct++) {
            int col = (ct << 4) + (lane & 15);
            float bv = b1[col];
#pragma unroll
            for (int r = 0; r < 4; r++) {
                float v = fmaxf(acc[ct][r] + bv, 0.f);
                unsigned short hi = f2bf(v);
                unsigned short lo = f2bf(v - bf2f(hi));
                int row = r0 + r;
                int byte = row * 256 + ((col * 2) ^ ((row & 7) << 4));
                *(unsigned short*)((char*)Ahi + byte) = hi;
                *(unsigned short*)((char*)Alo + byte) = lo;
            }
            acc[ct] = (f32x4){0.f, 0.f, 0.f, 0.f};
        }
    }
    __syncthreads();
    compute(B2);

    // epilogue 2: cols 0-63 -> pb (bf16), cols 64-127 -> out (+b2, f32)
    {
        const int r0 = wtile * 16 + ((lane >> 4) << 2);
#pragma unroll
        for (int ct = 0; ct < 8; ct++) {
            int col = (ct << 4) + (lane & 15);
#pragma unroll
            for (int r = 0; r < 4; r++) {
                int node = block0 + r0 + r;
                if (node < N_NODES) {
                    if (ct < 4) pb[(size_t)node * DOUT + col] = f2bf(acc[ct][r]);
                    else out[(size_t)node * DOUT + (col - 64)] = acc[ct][r] + b2[col - 64];
                }
            }
        }
    }
}

// ---------------- gather layer-2 (wide): 8 edges/wave, 8 lanes x 8 dims -------
__global__ __launch_bounds__(256) void gather2_kernel(const int* __restrict__ row_ptr,
                                                      const int* __restrict__ csr,
                                                      const unsigned short* __restrict__ pb,
                                                      float* __restrict__ out) {
    int node = blockIdx.x * 4 + (threadIdx.x >> 6);
    if (node >= N_NODES) return;
    const int lane = threadIdx.x & 63;
    const int g = lane >> 3;  // edge slot 0..7
    const int sl = lane & 7;  // dim block: dims [8*sl, 8*sl+8)
    int beg = row_ptr[node], end = row_ptr[node + 1];
    float acc[8] = {0.f, 0.f, 0.f, 0.f, 0.f, 0.f, 0.f, 0.f};
    for (int base = beg + g; base < end; base += 8) {
        int s = csr[base];
        uint4 u = *(const uint4*)(pb + (size_t)s * DOUT + sl * 8);
        acc[0] += __uint_as_float(u.x << 16);
        acc[1] += __uint_as_float(u.x & 0xffff0000u);
        acc[2] += __uint_as_float(u.y << 16);
        acc[3] += __uint_as_float(u.y & 0xffff0000u);
        acc[4] += __uint_as_float(u.z << 16);
        acc[5] += __uint_as_float(u.z & 0xffff0000u);
        acc[6] += __uint_as_float(u.w << 16);
        acc[7] += __uint_as_float(u.w & 0xffff0000u);
    }
#pragma unroll
    for (int i = 0; i < 8; i++) {
        acc[i] += __shfl_xor(acc[i], 8, 64);
        acc[i] += __shfl_xor(acc[i], 16, 64);
        acc[i] += __shfl_xor(acc[i], 32, 64);
    }
    // lane (g,sl) owns dim 8*sl + g  (static-index select over g)
    float r;
    if (g == 0)      r = acc[0];
    else if (g == 1) r = acc[1];
    else if (g == 2) r = acc[2];
    else if (g == 3) r = acc[3];
    else if (g == 4) r = acc[4];
    else if (g == 5) r = acc[5];
    else if (g == 6) r = acc[6];
    else             r = acc[7];
    float invd = 1.0f / fmaxf((float)(end - beg), 1.0f);
    int d = sl * 8 + g;
    out[(size_t)node * DOUT + d] += r * invd;
}

extern "C" void kernel_launch(void* const* d_in, const int* in_sizes, int n_in,
                              void* d_out, int out_size, void* d_ws, size_t ws_size,
                              hipStream_t stream) {
    const float* x   = (const float*)d_in[0];
    const int*   ei  = (const int*)d_in[1];
    const float* w1l = (const float*)d_in[2];
    const float* b1  = (const float*)d_in[3];
    const float* w1r = (const float*)d_in[4];
    const float* w2l = (const float*)d_in[5];
    const float* b2  = (const float*)d_in[6];
    const float* w2r = (const float*)d_in[7];
    float* out = (float*)d_out;

    // workspace layout
    int* iw = (int*)d_ws;
    int* degi    = iw;                        // 50000
    int* row_ptr = iw + 50000;                // 50001
    int* cursor  = iw + 100001;               // 50000
    int* csr     = iw + 150001;               // 600000
    int* partial = iw + 750001;               // 256
    float* mean  = (float*)(iw + 750272);     // N*128 f32, 16B aligned
    unsigned short* xb  = (unsigned short*)(mean + (size_t)N_NODES * DIN);  // N*128 bf16
    unsigned short* pbb = xb + (size_t)N_NODES * DIN;                       // N*64 bf16
    unsigned short* bfr = pbb + (size_t)N_NODES * DOUT;                     // 3*16384 bf16
    const unsigned short* B1a = bfr;
    const unsigned short* B1b = bfr + 16384;
    const unsigned short* B2  = bfr + 32768;

    hipMemsetAsync(degi, 0, N_NODES * sizeof(int), stream);

    bprep_kernel<<<192, 256, 0, stream>>>(w1l, w1r, w2l, w2r, bfr);
    xcvt_kernel<<<(N_NODES * DIN / 4) / 256, 256, 0, stream>>>(x, xb);
    deg_kernel<<<(N_EDGES + 255) / 256, 256, 0, stream>>>(ei, degi);
    scanA_kernel<<<SCAN_BLOCKS, 256, 0, stream>>>(degi, partial);
    scanB_kernel<<<1, 256, 0, stream>>>(partial, row_ptr);
    scanC_kernel<<<SCAN_BLOCKS, 256, 0, stream>>>(degi, partial, row_ptr, cursor);
    fill_kernel<<<(N_EDGES + 255) / 256, 256, 0, stream>>>(ei, cursor, csr);

    gather1_kernel<<<(N_NODES + 3) / 4, 256, 0, stream>>>(row_ptr, csr, xb, mean);
    fused_kernel<<<(N_NODES + 63) / 64, 256, 0, stream>>>(mean, x, B1a, B1b, B2,
                                                          b1, b2, pbb, out);
    gather2_kernel<<<(N_NODES + 3) / 4, 256, 0, stream>>>(row_ptr, csr, pbb, out);
}

// Round 6
// 168.968 us; speedup vs baseline: 3.3902x; 1.0405x over previous
//
#include <hip/hip_runtime.h>

#define N_NODES 50000
#define N_EDGES 600000
#define DIN 128
#define HD 128
#define DOUT 64
#define SCAN_BLOCKS 196  // ceil(50000/256)

typedef float f32x4 __attribute__((ext_vector_type(4)));
typedef short bf16x8 __attribute__((ext_vector_type(8)));

__device__ __forceinline__ unsigned short f2bf(float f) {
    unsigned u = __float_as_uint(f);
    unsigned r = (u + 0x7FFFu + ((u >> 16) & 1u)) >> 16;
    return (unsigned short)r;
}
__device__ __forceinline__ float bf2f(unsigned short s) {
    return __uint_as_float(((unsigned)s) << 16);
}

// ---------------- zero degi (runtime fillBuffer was 43 us on a tiny grid) ----
__global__ __launch_bounds__(256) void zero_kernel(int* __restrict__ p) {
    int i = blockIdx.x * 256 + threadIdx.x;
    if (i < N_NODES) p[i] = 0;
}

// ---------------- degree histogram (int) ----------------
__global__ __launch_bounds__(256) void deg_kernel(const int* __restrict__ ei,
                                                  int* __restrict__ degi) {
    int e = blockIdx.x * 256 + threadIdx.x;
    if (e < N_EDGES) atomicAdd(&degi[ei[N_EDGES + e]], 1);
}

// ---------------- scan phase A: per-block (256-elem) sums ----------------
__global__ __launch_bounds__(256) void scanA_kernel(const int* __restrict__ degi,
                                                    int* __restrict__ partial) {
    int i = blockIdx.x * 256 + threadIdx.x;
    int v = (i < N_NODES) ? degi[i] : 0;
#pragma unroll
    for (int off = 32; off > 0; off >>= 1) v += __shfl_down(v, (unsigned)off, 64);
    __shared__ int ws[4];
    const int lane = threadIdx.x & 63, wid = threadIdx.x >> 6;
    if (lane == 0) ws[wid] = v;
    __syncthreads();
    if (threadIdx.x == 0) partial[blockIdx.x] = ws[0] + ws[1] + ws[2] + ws[3];
}

// ---------------- scan phase B: 1 block scans the partials ----------------
__global__ __launch_bounds__(256) void scanB_kernel(int* __restrict__ partial,
                                                    int* __restrict__ row_ptr) {
    const int lane = threadIdx.x & 63, wid = threadIdx.x >> 6;
    int i = threadIdx.x;
    int v = (i < SCAN_BLOCKS) ? partial[i] : 0;
    int incl = v;
#pragma unroll
    for (int off = 1; off < 64; off <<= 1) {
        int t = __shfl_up(incl, (unsigned)off, 64);
        if (lane >= off) incl += t;
    }
    __shared__ int ws[4];
    if (lane == 63) ws[wid] = incl;
    __syncthreads();
    int woff = 0;
    for (int w = 0; w < wid; w++) woff += ws[w];
    incl += woff;
    if (i < SCAN_BLOCKS) partial[i] = incl - v;
    if (i == 255) row_ptr[N_NODES] = incl;
}

// ---------------- scan phase C: local scan + block offset ----------------
__global__ __launch_bounds__(256) void scanC_kernel(const int* __restrict__ degi,
                                                    const int* __restrict__ partial,
                                                    int* __restrict__ row_ptr,
                                                    int* __restrict__ cursor) {
    const int lane = threadIdx.x & 63, wid = threadIdx.x >> 6;
    int i = blockIdx.x * 256 + threadIdx.x;
    int v = (i < N_NODES) ? degi[i] : 0;
    int incl = v;
#pragma unroll
    for (int off = 1; off < 64; off <<= 1) {
        int t = __shfl_up(incl, (unsigned)off, 64);
        if (lane >= off) incl += t;
    }
    __shared__ int ws[4];
    if (lane == 63) ws[wid] = incl;
    __syncthreads();
    int woff = 0;
    for (int w = 0; w < wid; w++) woff += ws[w];
    int excl = partial[blockIdx.x] + woff + incl - v;
    if (i < N_NODES) { row_ptr[i] = excl; cursor[i] = excl; }
}

// ---------------- CSR fill ----------------
__global__ __launch_bounds__(256) void fill_kernel(const int* __restrict__ ei,
                                                   int* __restrict__ cursor,
                                                   int* __restrict__ csr) {
    int e = blockIdx.x * 256 + threadIdx.x;
    if (e < N_EDGES) {
        int s = ei[e];
        int t = ei[N_EDGES + e];
        int pos = atomicAdd(&cursor[t], 1);
        csr[pos] = s;
    }
}

// ---------------- x -> bf16 ----------------
__global__ __launch_bounds__(256) void xcvt_kernel(const float* __restrict__ x,
                                                   unsigned short* __restrict__ xb) {
    int i = blockIdx.x * 256 + threadIdx.x;
    float4 v = ((const float4*)x)[i];
    ushort4 o;
    o.x = f2bf(v.x); o.y = f2bf(v.y); o.z = f2bf(v.z); o.w = f2bf(v.w);
    ((ushort4*)xb)[i] = o;
}

// ---------------- gather layer-1: 4 edge slots x 2 edges in flight ------------
__global__ __launch_bounds__(256) void gather1_kernel(const int* __restrict__ row_ptr,
                                                      const int* __restrict__ csr,
                                                      const unsigned short* __restrict__ xb,
                                                      float* __restrict__ mean) {
    int node = blockIdx.x * 4 + (threadIdx.x >> 6);
    if (node >= N_NODES) return;
    const int lane = threadIdx.x & 63;
    const int g = lane >> 4;   // edge slot 0..3
    const int sl = lane & 15;  // dim block: dims [8*sl, 8*sl+8)
    int beg = row_ptr[node], end = row_ptr[node + 1];
    float acc[8] = {0.f, 0.f, 0.f, 0.f, 0.f, 0.f, 0.f, 0.f};
    int base = beg + g;
    for (; base + 4 < end; base += 8) {  // two independent loads per iter (MLP=2)
        int s0 = csr[base];
        int s1 = csr[base + 4];
        uint4 u0 = *(const uint4*)(xb + (size_t)s0 * DIN + sl * 8);
        uint4 u1 = *(const uint4*)(xb + (size_t)s1 * DIN + sl * 8);
        acc[0] += __uint_as_float(u0.x << 16) + __uint_as_float(u1.x << 16);
        acc[1] += __uint_as_float(u0.x & 0xffff0000u) + __uint_as_float(u1.x & 0xffff0000u);
        acc[2] += __uint_as_float(u0.y << 16) + __uint_as_float(u1.y << 16);
        acc[3] += __uint_as_float(u0.y & 0xffff0000u) + __uint_as_float(u1.y & 0xffff0000u);
        acc[4] += __uint_as_float(u0.z << 16) + __uint_as_float(u1.z << 16);
        acc[5] += __uint_as_float(u0.z & 0xffff0000u) + __uint_as_float(u1.z & 0xffff0000u);
        acc[6] += __uint_as_float(u0.w << 16) + __uint_as_float(u1.w << 16);
        acc[7] += __uint_as_float(u0.w & 0xffff0000u) + __uint_as_float(u1.w & 0xffff0000u);
    }
    if (base < end) {
        int s0 = csr[base];
        uint4 u = *(const uint4*)(xb + (size_t)s0 * DIN + sl * 8);
        acc[0] += __uint_as_float(u.x << 16);
        acc[1] += __uint_as_float(u.x & 0xffff0000u);
        acc[2] += __uint_as_float(u.y << 16);
        acc[3] += __uint_as_float(u.y & 0xffff0000u);
        acc[4] += __uint_as_float(u.z << 16);
        acc[5] += __uint_as_float(u.z & 0xffff0000u);
        acc[6] += __uint_as_float(u.w << 16);
        acc[7] += __uint_as_float(u.w & 0xffff0000u);
    }
#pragma unroll
    for (int i = 0; i < 8; i++) {
        acc[i] += __shfl_xor(acc[i], 16, 64);
        acc[i] += __shfl_xor(acc[i], 32, 64);
    }
    float r0, r1;
    if (g == 0)      { r0 = acc[0]; r1 = acc[1]; }
    else if (g == 1) { r0 = acc[2]; r1 = acc[3]; }
    else if (g == 2) { r0 = acc[4]; r1 = acc[5]; }
    else             { r0 = acc[6]; r1 = acc[7]; }
    float invd = 1.0f / fmaxf((float)(end - beg), 1.0f);
    float2 r; r.x = r0 * invd; r.y = r1 * invd;
    *(float2*)(mean + (size_t)node * DIN + sl * 8 + g * 2) = r;
}

// ---------------- weight fragment prep (f32 -> bf16 MFMA fragment arrays) ----
__global__ __launch_bounds__(256) void bprep_kernel(const float* __restrict__ w1l,
                                                    const float* __restrict__ w1r,
                                                    const float* __restrict__ w2l,
                                                    const float* __restrict__ w2r,
                                                    unsigned short* __restrict__ bfr) {
    int tid = blockIdx.x * 256 + threadIdx.x;  // < 3*16384
    int a = tid >> 14;
    int r = tid & 16383;
    int j = r & 7, lane = (r >> 3) & 63, kc = (r >> 9) & 3, ct = r >> 11;
    int k = kc * 32 + ((lane >> 4) << 3) + j;
    int c = (ct << 4) + (lane & 15);
    float v;
    if (a == 0) v = w1l[k * HD + c];
    else if (a == 1) v = w1r[k * HD + c];
    else v = (c < 64) ? w2l[k * DOUT + c] : w2r[k * DOUT + (c - 64)];
    bfr[tid] = f2bf(v);
}

// ---------------- fused MFMA: h=relu(mean@w1l + x@w1r + b1); p=h@w2l; out=h@w2r+b2
// T14 async-stage: both A-tiles' global loads issued at kernel entry into
// registers; LDS conversion/writes deferred so x's load latency hides under
// the first MFMA phase.
__global__ __launch_bounds__(256) void fused_kernel(
    const float* __restrict__ mean, const float* __restrict__ x,
    const unsigned short* __restrict__ B1a, const unsigned short* __restrict__ B1b,
    const unsigned short* __restrict__ B2,
    const float* __restrict__ b1, const float* __restrict__ b2,
    unsigned short* __restrict__ pb, float* __restrict__ out) {
    __shared__ unsigned short Ahi[64 * 128];
    __shared__ unsigned short Alo[64 * 128];
    const int block0 = blockIdx.x * 64;
    const int lane = threadIdx.x & 63;
    const int wtile = threadIdx.x >> 6;

    // --- issue ALL global loads for both tiles up-front (registers) ---
    float4 mv[8], xv[8];
#pragma unroll
    for (int i = 0; i < 8; i++) {
        int f = threadIdx.x + i * 256;
        int row = f >> 5;
        int c4 = f & 31;
        int rg = block0 + row;
        if (rg >= N_NODES) rg = N_NODES - 1;
        mv[i] = *(const float4*)(mean + (size_t)rg * 128 + c4 * 4);
        xv[i] = *(const float4*)(x + (size_t)rg * 128 + c4 * 4);
    }

    f32x4 acc[8];
#pragma unroll
    for (int t = 0; t < 8; t++) acc[t] = (f32x4){0.f, 0.f, 0.f, 0.f};

    auto write_tile = [&](const float4* v8) {
#pragma unroll
        for (int i = 0; i < 8; i++) {
            int f = threadIdx.x + i * 256;
            int row = f >> 5;
            int c4 = f & 31;
            float4 v = v8[i];
            ushort4 hi, lo;
            hi.x = f2bf(v.x); lo.x = f2bf(v.x - bf2f(hi.x));
            hi.y = f2bf(v.y); lo.y = f2bf(v.y - bf2f(hi.y));
            hi.z = f2bf(v.z); lo.z = f2bf(v.z - bf2f(hi.z));
            hi.w = f2bf(v.w); lo.w = f2bf(v.w - bf2f(hi.w));
            int byte = row * 256 + ((c4 * 8) ^ ((row & 7) << 4));
            *(ushort4*)((char*)Ahi + byte) = hi;
            *(ushort4*)((char*)Alo + byte) = lo;
        }
    };

    auto compute = [&](const unsigned short* __restrict__ Bf) {
        const int arow = wtile * 16 + (lane & 15);
        const int swz = (arow & 7) << 4;
#pragma unroll
        for (int kc = 0; kc < 4; kc++) {
            int byte = arow * 256 + ((kc * 64 + ((lane >> 4) << 4)) ^ swz);
            bf16x8 ahi = *(const bf16x8*)((const char*)Ahi + byte);
            bf16x8 alo = *(const bf16x8*)((const char*)Alo + byte);
#pragma unroll
            for (int ct = 0; ct < 8; ct++) {
                bf16x8 b = *(const bf16x8*)(Bf + ((((ct << 2) + kc) << 6) + lane) * 8);
                acc[ct] = __builtin_amdgcn_mfma_f32_16x16x32_bf16(ahi, b, acc[ct], 0, 0, 0);
                acc[ct] = __builtin_amdgcn_mfma_f32_16x16x32_bf16(alo, b, acc[ct], 0, 0, 0);
            }
        }
    };

    write_tile(mv);                 // waits only on mv loads
    __syncthreads();
    compute(B1a);                   // x loads still in flight underneath
    __syncthreads();
    write_tile(xv);
    __syncthreads();
    compute(B1b);
    __syncthreads();

    // epilogue 1: h = relu(acc + b1) -> restage as bf16 hi/lo A-tile
    {
        const int r0 = wtile * 16 + ((lane >> 4) << 2);
#pragma unroll
        for (int ct = 0; ct < 8; ct++) {
            int col = (ct << 4) + (lane & 15);
            float bv = b1[col];
#pragma unroll
            for (int r = 0; r < 4; r++) {
                float v = fmaxf(acc[ct][r] + bv, 0.f);
                unsigned short hi = f2bf(v);
                unsigned short lo = f2bf(v - bf2f(hi));
                int row = r0 + r;
                int byte = row * 256 + ((col * 2) ^ ((row & 7) << 4));
                *(unsigned short*)((char*)Ahi + byte) = hi;
                *(unsigned short*)((char*)Alo + byte) = lo;
            }
            acc[ct] = (f32x4){0.f, 0.f, 0.f, 0.f};
        }
    }
    __syncthreads();
    compute(B2);

    // epilogue 2: cols 0-63 -> pb (bf16), cols 64-127 -> out (+b2, f32)
    {
        const int r0 = wtile * 16 + ((lane >> 4) << 2);
#pragma unroll
        for (int ct = 0; ct < 8; ct++) {
            int col = (ct << 4) + (lane & 15);
#pragma unroll
            for (int r = 0; r < 4; r++) {
                int node = block0 + r0 + r;
                if (node < N_NODES) {
                    if (ct < 4) pb[(size_t)node * DOUT + col] = f2bf(acc[ct][r]);
                    else out[(size_t)node * DOUT + (col - 64)] = acc[ct][r] + b2[col - 64];
                }
            }
        }
    }
}

// ---------------- gather layer-2: 8 edge slots x 2 edges in flight ------------
__global__ __launch_bounds__(256) void gather2_kernel(const int* __restrict__ row_ptr,
                                                      const int* __restrict__ csr,
                                                      const unsigned short* __restrict__ pb,
                                                      float* __restrict__ out) {
    int node = blockIdx.x * 4 + (threadIdx.x >> 6);
    if (node >= N_NODES) return;
    const int lane = threadIdx.x & 63;
    const int g = lane >> 3;  // edge slot 0..7
    const int sl = lane & 7;  // dim block: dims [8*sl, 8*sl+8)
    int beg = row_ptr[node], end = row_ptr[node + 1];
    float acc[8] = {0.f, 0.f, 0.f, 0.f, 0.f, 0.f, 0.f, 0.f};
    int base = beg + g;
    for (; base + 8 < end; base += 16) {  // two independent loads per iter
        int s0 = csr[base];
        int s1 = csr[base + 8];
        uint4 u0 = *(const uint4*)(pb + (size_t)s0 * DOUT + sl * 8);
        uint4 u1 = *(const uint4*)(pb + (size_t)s1 * DOUT + sl * 8);
        acc[0] += __uint_as_float(u0.x << 16) + __uint_as_float(u1.x << 16);
        acc[1] += __uint_as_float(u0.x & 0xffff0000u) + __uint_as_float(u1.x & 0xffff0000u);
        acc[2] += __uint_as_float(u0.y << 16) + __uint_as_float(u1.y << 16);
        acc[3] += __uint_as_float(u0.y & 0xffff0000u) + __uint_as_float(u1.y & 0xffff0000u);
        acc[4] += __uint_as_float(u0.z << 16) + __uint_as_float(u1.z << 16);
        acc[5] += __uint_as_float(u0.z & 0xffff0000u) + __uint_as_float(u1.z & 0xffff0000u);
        acc[6] += __uint_as_float(u0.w << 16) + __uint_as_float(u1.w << 16);
        acc[7] += __uint_as_float(u0.w & 0xffff0000u) + __uint_as_float(u1.w & 0xffff0000u);
    }
    if (base < end) {
        int s0 = csr[base];
        uint4 u = *(const uint4*)(pb + (size_t)s0 * DOUT + sl * 8);
        acc[0] += __uint_as_float(u.x << 16);
        acc[1] += __uint_as_float(u.x & 0xffff0000u);
        acc[2] += __uint_as_float(u.y << 16);
        acc[3] += __uint_as_float(u.y & 0xffff0000u);
        acc[4] += __uint_as_float(u.z << 16);
        acc[5] += __uint_as_float(u.z & 0xffff0000u);
        acc[6] += __uint_as_float(u.w << 16);
        acc[7] += __uint_as_float(u.w & 0xffff0000u);
    }
#pragma unroll
    for (int i = 0; i < 8; i++) {
        acc[i] += __shfl_xor(acc[i], 8, 64);
        acc[i] += __shfl_xor(acc[i], 16, 64);
        acc[i] += __shfl_xor(acc[i], 32, 64);
    }
    float r;
    if (g == 0)      r = acc[0];
    else if (g == 1) r = acc[1];
    else if (g == 2) r = acc[2];
    else if (g == 3) r = acc[3];
    else if (g == 4) r = acc[4];
    else if (g == 5) r = acc[5];
    else if (g == 6) r = acc[6];
    else             r = acc[7];
    float invd = 1.0f / fmaxf((float)(end - beg), 1.0f);
    int d = sl * 8 + g;
    out[(size_t)node * DOUT + d] += r * invd;
}

extern "C" void kernel_launch(void* const* d_in, const int* in_sizes, int n_in,
                              void* d_out, int out_size, void* d_ws, size_t ws_size,
                              hipStream_t stream) {
    const float* x   = (const float*)d_in[0];
    const int*   ei  = (const int*)d_in[1];
    const float* w1l = (const float*)d_in[2];
    const float* b1  = (const float*)d_in[3];
    const float* w1r = (const float*)d_in[4];
    const float* w2l = (const float*)d_in[5];
    const float* b2  = (const float*)d_in[6];
    const float* w2r = (const float*)d_in[7];
    float* out = (float*)d_out;

    // workspace layout
    int* iw = (int*)d_ws;
    int* degi    = iw;                        // 50000
    int* row_ptr = iw + 50000;                // 50001
    int* cursor  = iw + 100001;               // 50000
    int* csr     = iw + 150001;               // 600000
    int* partial = iw + 750001;               // 256
    float* mean  = (float*)(iw + 750272);     // N*128 f32, 16B aligned
    unsigned short* xb  = (unsigned short*)(mean + (size_t)N_NODES * DIN);  // N*128 bf16
    unsigned short* pbb = xb + (size_t)N_NODES * DIN;                       // N*64 bf16
    unsigned short* bfr = pbb + (size_t)N_NODES * DOUT;                     // 3*16384 bf16
    const unsigned short* B1a = bfr;
    const unsigned short* B1b = bfr + 16384;
    const unsigned short* B2  = bfr + 32768;

    zero_kernel<<<SCAN_BLOCKS, 256, 0, stream>>>(degi);
    bprep_kernel<<<192, 256, 0, stream>>>(w1l, w1r, w2l, w2r, bfr);
    xcvt_kernel<<<(N_NODES * DIN / 4) / 256, 256, 0, stream>>>(x, xb);
    deg_kernel<<<(N_EDGES + 255) / 256, 256, 0, stream>>>(ei, degi);
    scanA_kernel<<<SCAN_BLOCKS, 256, 0, stream>>>(degi, partial);
    scanB_kernel<<<1, 256, 0, stream>>>(partial, row_ptr);
    scanC_kernel<<<SCAN_BLOCKS, 256, 0, stream>>>(degi, partial, row_ptr, cursor);
    fill_kernel<<<(N_EDGES + 255) / 256, 256, 0, stream>>>(ei, cursor, csr);

    gather1_kernel<<<(N_NODES + 3) / 4, 256, 0, stream>>>(row_ptr, csr, xb, mean);
    fused_kernel<<<(N_NODES + 63) / 64, 256, 0, stream>>>(mean, x, B1a, B1b, B2,
                                                          b1, b2, pbb, out);
    gather2_kernel<<<(N_NODES + 3) / 4, 256, 0, stream>>>(row_ptr, csr, pbb, out);
}